// Round 5
// baseline (922.551 us; speedup 1.0000x reference)
//
#include <hip/hip_runtime.h>
#include <hip/hip_bf16.h>

#define N_NODES 20000
#define N_REL 32
#define HID 128
#define EMB 16
#define N_EDGES 600000
#define NB (N_NODES * N_REL)   // 640000 bins

typedef __attribute__((ext_vector_type(8))) short  bf8v;   // 8 bf16 (MFMA A/B frag)
typedef __attribute__((ext_vector_type(8))) unsigned short us8v; // 16-byte unit
typedef __attribute__((ext_vector_type(4))) float  f4v;    // MFMA C/D frag

__device__ __forceinline__ unsigned short f2b(float f) {
    __hip_bfloat16 h = __float2bfloat16(f);
    return __builtin_bit_cast(unsigned short, h);
}
__device__ __forceinline__ float b2f(unsigned short u) {
    unsigned int x = ((unsigned int)u) << 16;
    return __builtin_bit_cast(float, x);
}

// ---- binning: histogram over (dst, rel) bins ----
__global__ void hist_k(const int* __restrict__ dst, const int* __restrict__ et,
                       int* __restrict__ hist) {
    int e = blockIdx.x * 256 + threadIdx.x;
    if (e < N_EDGES) atomicAdd(&hist[dst[e] * N_REL + et[e]], 1);
}

__global__ void inv_k(const int* __restrict__ hist, float* __restrict__ inv) {
    int i = blockIdx.x * 256 + threadIdx.x;
    if (i < NB) {
        int c = hist[i];
        inv[i] = c > 0 ? 1.0f / (float)c : 0.0f;
    }
}

// ---- 2-level exclusive scan over NB = 625 blocks x 1024 ----
__global__ void scan1_k(const int* __restrict__ hist, int* __restrict__ binoff,
                        int* __restrict__ bsum) {
    __shared__ int sh[256];
    const int t = threadIdx.x;
    const int base = blockIdx.x * 1024 + t * 4;
    int4 h4 = *(const int4*)(hist + base);
    int ts = h4.x + h4.y + h4.z + h4.w;
    sh[t] = ts;
    __syncthreads();
    for (int o = 1; o < 256; o <<= 1) {
        int v = (t >= o) ? sh[t - o] : 0;
        __syncthreads();
        sh[t] += v;
        __syncthreads();
    }
    int exc = sh[t] - ts;
    binoff[base + 0] = exc;
    binoff[base + 1] = exc + h4.x;
    binoff[base + 2] = exc + h4.x + h4.y;
    binoff[base + 3] = exc + h4.x + h4.y + h4.z;
    if (t == 255) bsum[blockIdx.x] = sh[255];
}

__global__ void scan2_k(const int* __restrict__ bsum, int* __restrict__ bbase) {
    __shared__ int sh[1024];
    const int t = threadIdx.x;
    int v = (t < 625) ? bsum[t] : 0;
    sh[t] = v;
    __syncthreads();
    for (int o = 1; o < 1024; o <<= 1) {
        int u = (t >= o) ? sh[t - o] : 0;
        __syncthreads();
        sh[t] += u;
        __syncthreads();
    }
    if (t < 625) bbase[t] = sh[t] - v;
}

__global__ void scan3_k(int* __restrict__ binoff, const int* __restrict__ bbase,
                        int* __restrict__ cursors) {
    int i = blockIdx.x * 256 + threadIdx.x;
    if (i < NB) {
        int v = binoff[i] + bbase[i >> 10];
        binoff[i] = v;
        cursors[i] = v;
    }
    if (i == 0) binoff[NB] = N_EDGES;
}

__global__ void scatter_k(const int* __restrict__ src, const int* __restrict__ dst,
                          const int* __restrict__ et, int* __restrict__ cursors,
                          int* __restrict__ ssrc) {
    int e = blockIdx.x * 256 + threadIdx.x;
    if (e < N_EDGES) {
        int b = dst[e] * N_REL + et[e];
        int p = atomicAdd(&cursors[b], 1);
        ssrc[p] = src[e];
    }
}

// ---- bf16 conversion / transpose kernels ----
__global__ void conv_x_k(const float* __restrict__ x, unsigned short* __restrict__ xb) {
    int i = blockIdx.x * 256 + threadIdx.x;
    if (i >= N_NODES * 32) return;
    int n = i >> 5, k = i & 31;
    xb[i] = (k < EMB) ? f2b(x[n * EMB + k]) : (unsigned short)0;
}
__global__ void conv_w1_k(const float* __restrict__ W1, unsigned short* __restrict__ w1t) {
    int i = blockIdx.x * 256 + threadIdx.x;
    if (i >= N_REL * HID * 32) return;
    int r = i >> 12, n = (i >> 5) & 127, k = i & 31;
    w1t[i] = (k < EMB) ? f2b(W1[r * EMB * HID + k * HID + n]) : (unsigned short)0;
}
__global__ void conv_r1_k(const float* __restrict__ root1, unsigned short* __restrict__ r1t) {
    int i = blockIdx.x * 256 + threadIdx.x;
    if (i >= HID * 32) return;
    int n = i >> 5, k = i & 31;
    r1t[i] = (k < EMB) ? f2b(root1[k * HID + n]) : (unsigned short)0;
}
__global__ void conv_w2_k(const float* __restrict__ W2, unsigned short* __restrict__ w2t) {
    int i = blockIdx.x * 256 + threadIdx.x;
    if (i >= N_REL * HID * HID) return;
    int r = i >> 14, n = (i >> 7) & 127, k = i & 127;
    w2t[i] = f2b(W2[r * HID * HID + k * HID + n]);
}
__global__ void conv_r2_k(const float* __restrict__ root2, unsigned short* __restrict__ r2t) {
    int i = blockIdx.x * 256 + threadIdx.x;
    if (i >= HID * HID) return;
    int n = i >> 7, k = i & 127;
    r2t[i] = f2b(root2[k * HID + n]);
}

// ---- fused aggregate + transform GEMM, flat-worklist gather, no global atomics ----
// Block: 256 threads = 4 waves; 32 dst rows x 128 cols (wave w -> cols 32w..32w+31).
// grid = (625). KT = K/32; LSF = f32 LDS row stride; C16S = log2(16B chunks per row).
template<int KT, int LSF, int C16S, bool L1>
__global__ __launch_bounds__(256) void gemm_k(
    const int* __restrict__ binoff, const float* __restrict__ inv,
    const int* __restrict__ ssrc,
    const unsigned short* __restrict__ G,    // bf16 rows [*, KT*32]
    const unsigned short* __restrict__ Bw,   // bf16 W^T [r][128][KT*32]
    const unsigned short* __restrict__ Br,   // bf16 root^T [128][KT*32]
    const float* __restrict__ bias,
    void* __restrict__ outp) {

    constexpr int ROW = KT * 32;       // bf16 per A-row
    constexpr int C16 = 1 << C16S;     // 16B chunks per row
    constexpr int NZ4 = 32 * LSF / 4;  // float4 count for zeroing

    __shared__ float Asf[32 * LSF];
    __shared__ int   estart[32];
    __shared__ int   soffL[32];
    __shared__ float sinvL[32];
    __shared__ int   ntotL;

    const int t = threadIdx.x;
    const int w = t >> 6, lane = t & 63;
    const int q = lane >> 4, m16 = lane & 15;
    const int d0 = blockIdx.x * 32;
    const int colb = w * 32;

    f4v acc[2][2];
#pragma unroll
    for (int rt = 0; rt < 2; ++rt)
#pragma unroll
        for (int ct = 0; ct < 2; ++ct) acc[rt][ct] = f4v{0.f, 0.f, 0.f, 0.f};

    for (int it = 0; it < N_REL; ++it) {
        // B fragments for this relation (issued early; waited at MFMA)
        const unsigned short* Bp = Bw + (size_t)it * HID * ROW;
        bf8v bfr[2][KT];
#pragma unroll
        for (int ct = 0; ct < 2; ++ct) {
            const int n = colb + 16 * ct + m16;
#pragma unroll
            for (int ks = 0; ks < KT; ++ks)
                bfr[ct][ks] = *(const bf8v*)(Bp + (size_t)n * ROW + ks * 32 + q * 8);
        }

        __syncthreads();   // previous iteration's LDS reads complete

        // meta + 32-lane shuffle scan (wave 0, lanes 0..31)
        if (t < 32) {
            int b = (d0 + t) * N_REL + it;
            int so = binoff[b];
            int cnt = binoff[b + 1] - so;
            sinvL[t] = inv[b];
            soffL[t] = so;
            int v = cnt;
#pragma unroll
            for (int o = 1; o < 32; o <<= 1) {
                int u = __shfl_up(v, o, 32);
                if (t >= o) v += u;
            }
            estart[t] = v - cnt;
            if (t == 31) ntotL = v;
        }
        // zero fp32 A-tile
#pragma unroll
        for (int u = t; u < NZ4; u += 256) ((float4*)Asf)[u] = float4{0.f, 0.f, 0.f, 0.f};
        __syncthreads();

        // flat-worklist gather: item = (edge, chunk16); one-ahead prefetch
        const int nit = ntotL << C16S;
        int i = t;
        us8v hv; int row = 0, cc = 0;
        if (i < nit) {
            int e = i >> C16S; cc = i & (C16 - 1);
            int lo = 0;
#pragma unroll
            for (int o = 16; o >= 1; o >>= 1)
                if (lo + o < 32 && estart[lo + o] <= e) lo += o;
            row = lo;
            int s = ssrc[soffL[row] + (e - estart[row])];
            hv = *(const us8v*)(G + (size_t)s * ROW + cc * 8);
        }
        while (i < nit) {
            us8v ch = hv; int crow = row; int ccc = cc;
            int i2 = i + 256;
            if (i2 < nit) {
                int e = i2 >> C16S; cc = i2 & (C16 - 1);
                int lo = 0;
#pragma unroll
                for (int o = 16; o >= 1; o >>= 1)
                    if (lo + o < 32 && estart[lo + o] <= e) lo += o;
                row = lo;
                int s = ssrc[soffL[row] + (e - estart[row])];
                hv = *(const us8v*)(G + (size_t)s * ROW + cc * 8);
            }
            float* dp = &Asf[crow * LSF + ccc * 8];
#pragma unroll
            for (int j = 0; j < 8; ++j) atomicAdd(&dp[j], b2f(ch[j]));
            i = i2;
        }
        __syncthreads();

        // A fragments from fp32 LDS (scale by inv, cvt to bf16) + MFMA
#pragma unroll
        for (int rt = 0; rt < 2; ++rt) {
            const int r = m16 + 16 * rt;
            const float iv = sinvL[r];
            const float* ar = &Asf[r * LSF];
#pragma unroll
            for (int ks = 0; ks < KT; ++ks) {
                float4 va = *(const float4*)(ar + ks * 32 + q * 8);
                float4 vb = *(const float4*)(ar + ks * 32 + q * 8 + 4);
                us8v tmp;
                tmp[0] = f2b(va.x * iv); tmp[1] = f2b(va.y * iv);
                tmp[2] = f2b(va.z * iv); tmp[3] = f2b(va.w * iv);
                tmp[4] = f2b(vb.x * iv); tmp[5] = f2b(vb.y * iv);
                tmp[6] = f2b(vb.z * iv); tmp[7] = f2b(vb.w * iv);
                bf8v af = __builtin_bit_cast(bf8v, tmp);
#pragma unroll
                for (int ct = 0; ct < 2; ++ct)
                    acc[rt][ct] = __builtin_amdgcn_mfma_f32_16x16x32_bf16(af, bfr[ct][ks], acc[rt][ct], 0, 0, 0);
            }
        }
    }

    // root transform: fragments straight from global (no LDS)
#pragma unroll
    for (int rt = 0; rt < 2; ++rt) {
#pragma unroll
        for (int ks = 0; ks < KT; ++ks) {
            bf8v af = *(const bf8v*)(G + (size_t)(d0 + m16 + 16 * rt) * ROW + ks * 32 + q * 8);
#pragma unroll
            for (int ct = 0; ct < 2; ++ct) {
                bf8v bfr = *(const bf8v*)(Br + (size_t)(colb + 16 * ct + m16) * ROW + ks * 32 + q * 8);
                acc[rt][ct] = __builtin_amdgcn_mfma_f32_16x16x32_bf16(af, bfr, acc[rt][ct], 0, 0, 0);
            }
        }
    }

    // epilogue: direct stores
#pragma unroll
    for (int ct = 0; ct < 2; ++ct) {
        const int col = colb + 16 * ct + m16;
        const float bc = bias[col];
#pragma unroll
        for (int rt = 0; rt < 2; ++rt) {
#pragma unroll
            for (int g = 0; g < 4; ++g) {
                const int rr = 16 * rt + q * 4 + g;
                if constexpr (L1) {
                    ((unsigned short*)outp)[(size_t)(d0 + rr) * HID + col] =
                        f2b(fmaxf(acc[rt][ct][g] + bc, 0.0f));
                } else {
                    ((float*)outp)[(size_t)(d0 + rr) * HID + col] = acc[rt][ct][g] + bc;
                }
            }
        }
    }
}

extern "C" void kernel_launch(void* const* d_in, const int* in_sizes, int n_in,
                              void* d_out, int out_size, void* d_ws, size_t ws_size,
                              hipStream_t stream) {
    const int*   ei    = (const int*)d_in[0];   // [2, E]
    const int*   et    = (const int*)d_in[1];   // [E]
    const float* x     = (const float*)d_in[2]; // [N, 16]
    const float* W1    = (const float*)d_in[3]; // [32, 16, 128]
    const float* root1 = (const float*)d_in[4]; // [16, 128]
    const float* b1    = (const float*)d_in[5]; // [128]
    const float* W2    = (const float*)d_in[6]; // [32, 128, 128]
    const float* root2 = (const float*)d_in[7]; // [128, 128]
    const float* b2    = (const float*)d_in[8]; // [128]
    float* out = (float*)d_out;

    // ---- workspace layout ----
    char* ws = (char*)d_ws;
    size_t off = 0;
    auto alloc = [&](size_t bytes) { void* p = ws + off; off = (off + bytes + 63) & ~(size_t)63; return p; };
    int*   hist    = (int*)  alloc((size_t)NB * 4);
    int*   binoff  = (int*)  alloc((size_t)(NB + 1) * 4);
    int*   cursors = (int*)  alloc((size_t)NB * 4);
    float* inv     = (float*)alloc((size_t)NB * 4);
    int*   bsum    = (int*)  alloc(625 * 4);
    int*   bbase   = (int*)  alloc(625 * 4);
    int*   ssrc    = (int*)  alloc((size_t)N_EDGES * 4);
    unsigned short* xb  = (unsigned short*)alloc((size_t)N_NODES * 32 * 2);
    unsigned short* h1b = (unsigned short*)alloc((size_t)N_NODES * HID * 2);
    unsigned short* w1t = (unsigned short*)alloc((size_t)N_REL * HID * 32 * 2);
    unsigned short* r1t = (unsigned short*)alloc((size_t)HID * 32 * 2);
    unsigned short* w2t = (unsigned short*)alloc((size_t)N_REL * HID * HID * 2);
    unsigned short* r2t = (unsigned short*)alloc((size_t)HID * HID * 2);

    const int* src = ei;
    const int* dst = ei + N_EDGES;

    hipMemsetAsync(hist, 0, (size_t)NB * 4, stream);

    // binning
    hist_k<<<(N_EDGES + 255) / 256, 256, 0, stream>>>(dst, et, hist);
    inv_k<<<(NB + 255) / 256, 256, 0, stream>>>(hist, inv);
    scan1_k<<<NB / 1024, 256, 0, stream>>>(hist, binoff, bsum);
    scan2_k<<<1, 1024, 0, stream>>>(bsum, bbase);
    scan3_k<<<(NB + 255) / 256, 256, 0, stream>>>(binoff, bbase, cursors);
    scatter_k<<<(N_EDGES + 255) / 256, 256, 0, stream>>>(src, dst, et, cursors, ssrc);

    // bf16 conversions
    conv_x_k<<<(N_NODES * 32 + 255) / 256, 256, 0, stream>>>(x, xb);
    conv_w1_k<<<(N_REL * HID * 32 + 255) / 256, 256, 0, stream>>>(W1, w1t);
    conv_r1_k<<<(HID * 32 + 255) / 256, 256, 0, stream>>>(root1, r1t);
    conv_w2_k<<<(N_REL * HID * HID + 255) / 256, 256, 0, stream>>>(W2, w2t);
    conv_r2_k<<<(HID * HID + 255) / 256, 256, 0, stream>>>(root2, r2t);

    // layer 1: writes h1b = bf16(relu(.)) ; KT=1, LSF=36, C16=4 (log2=2)
    gemm_k<1, 36, 2, true><<<625, 256, 0, stream>>>(
        binoff, inv, ssrc, xb, w1t, r1t, b1, h1b);

    // layer 2: writes out fp32 ; KT=4, LSF=132, C16=16 (log2=4)
    gemm_k<4, 132, 4, false><<<625, 256, 0, stream>>>(
        binoff, inv, ssrc, h1b, w2t, r2t, b2, out);
}

// Round 7
// 363.778 us; speedup vs baseline: 2.5360x; 2.5360x over previous
//
#include <hip/hip_runtime.h>
#include <hip/hip_bf16.h>

#define N_NODES 20000
#define N_REL 32
#define HID 128
#define EMB 16
#define N_EDGES 600000
#define NB (N_NODES * N_REL)   // 640000 bins

typedef __attribute__((ext_vector_type(8))) short  bf8v;   // 8 bf16 (MFMA A/B frag)
typedef __attribute__((ext_vector_type(8))) unsigned short us8v; // 16-byte unit
typedef __attribute__((ext_vector_type(4))) float  f4v;    // MFMA C/D frag

__device__ __forceinline__ unsigned short f2b(float f) {
    __hip_bfloat16 h = __float2bfloat16(f);
    return __builtin_bit_cast(unsigned short, h);
}
__device__ __forceinline__ float b2f(unsigned short u) {
    unsigned int x = ((unsigned int)u) << 16;
    return __builtin_bit_cast(float, x);
}

// ---- binning: histogram over (dst, rel) bins ----
__global__ void hist_k(const int* __restrict__ dst, const int* __restrict__ et,
                       int* __restrict__ hist) {
    int e = blockIdx.x * 256 + threadIdx.x;
    if (e < N_EDGES) atomicAdd(&hist[dst[e] * N_REL + et[e]], 1);
}

__global__ void inv_k(const int* __restrict__ hist, float* __restrict__ inv) {
    int i = blockIdx.x * 256 + threadIdx.x;
    if (i < NB) {
        int c = hist[i];
        inv[i] = c > 0 ? 1.0f / (float)c : 0.0f;
    }
}

// ---- 2-level exclusive scan over NB = 625 blocks x 1024 ----
__global__ void scan1_k(const int* __restrict__ hist, int* __restrict__ binoff,
                        int* __restrict__ bsum) {
    __shared__ int sh[256];
    const int t = threadIdx.x;
    const int base = blockIdx.x * 1024 + t * 4;
    int4 h4 = *(const int4*)(hist + base);
    int ts = h4.x + h4.y + h4.z + h4.w;
    sh[t] = ts;
    __syncthreads();
    for (int o = 1; o < 256; o <<= 1) {
        int v = (t >= o) ? sh[t - o] : 0;
        __syncthreads();
        sh[t] += v;
        __syncthreads();
    }
    int exc = sh[t] - ts;
    binoff[base + 0] = exc;
    binoff[base + 1] = exc + h4.x;
    binoff[base + 2] = exc + h4.x + h4.y;
    binoff[base + 3] = exc + h4.x + h4.y + h4.z;
    if (t == 255) bsum[blockIdx.x] = sh[255];
}

__global__ void scan2_k(const int* __restrict__ bsum, int* __restrict__ bbase) {
    __shared__ int sh[1024];
    const int t = threadIdx.x;
    int v = (t < 625) ? bsum[t] : 0;
    sh[t] = v;
    __syncthreads();
    for (int o = 1; o < 1024; o <<= 1) {
        int u = (t >= o) ? sh[t - o] : 0;
        __syncthreads();
        sh[t] += u;
        __syncthreads();
    }
    if (t < 625) bbase[t] = sh[t] - v;
}

__global__ void scan3_k(int* __restrict__ binoff, const int* __restrict__ bbase,
                        int* __restrict__ cursors) {
    int i = blockIdx.x * 256 + threadIdx.x;
    if (i < NB) {
        int v = binoff[i] + bbase[i >> 10];
        binoff[i] = v;
        cursors[i] = v;
    }
    if (i == 0) binoff[NB] = N_EDGES;
}

__global__ void scatter_k(const int* __restrict__ src, const int* __restrict__ dst,
                          const int* __restrict__ et, int* __restrict__ cursors,
                          int* __restrict__ ssrc) {
    int e = blockIdx.x * 256 + threadIdx.x;
    if (e < N_EDGES) {
        int b = dst[e] * N_REL + et[e];
        int p = atomicAdd(&cursors[b], 1);
        ssrc[p] = src[e];
    }
}

// ---- bf16 conversion / transpose kernels ----
__global__ void conv_x_k(const float* __restrict__ x, unsigned short* __restrict__ xb) {
    int i = blockIdx.x * 256 + threadIdx.x;
    if (i >= N_NODES * 32) return;
    int n = i >> 5, k = i & 31;
    xb[i] = (k < EMB) ? f2b(x[n * EMB + k]) : (unsigned short)0;
}
__global__ void conv_w1_k(const float* __restrict__ W1, unsigned short* __restrict__ w1t) {
    int i = blockIdx.x * 256 + threadIdx.x;
    if (i >= N_REL * HID * 32) return;
    int r = i >> 12, n = (i >> 5) & 127, k = i & 31;
    w1t[i] = (k < EMB) ? f2b(W1[r * EMB * HID + k * HID + n]) : (unsigned short)0;
}
__global__ void conv_r1_k(const float* __restrict__ root1, unsigned short* __restrict__ r1t) {
    int i = blockIdx.x * 256 + threadIdx.x;
    if (i >= HID * 32) return;
    int n = i >> 5, k = i & 31;
    r1t[i] = (k < EMB) ? f2b(root1[k * HID + n]) : (unsigned short)0;
}
__global__ void conv_w2_k(const float* __restrict__ W2, unsigned short* __restrict__ w2t) {
    int i = blockIdx.x * 256 + threadIdx.x;
    if (i >= N_REL * HID * HID) return;
    int r = i >> 14, n = (i >> 7) & 127, k = i & 127;
    w2t[i] = f2b(W2[r * HID * HID + k * HID + n]);
}
__global__ void conv_r2_k(const float* __restrict__ root2, unsigned short* __restrict__ r2t) {
    int i = blockIdx.x * 256 + threadIdx.x;
    if (i >= HID * HID) return;
    int n = i >> 7, k = i & 127;
    r2t[i] = f2b(root2[k * HID + n]);
}

// ---- fused aggregate + transform GEMM ----
// Block: 256 threads = 4 waves; 32 dst rows x 128 cols (wave w -> cols 32w..32w+31).
// Gather: one (row, CW-short chunk) item per thread, serial loop over the bin's
// edges (avg ~1), fp32 sum in regs, CP8 ds_write_b128. Double-buffered LDS ->
// one barrier/iter. Meta + first-edge chain for it+1 prefetched right after
// the barrier so it completes behind the MFMA section.
// KT = K/32; LSS = LDS row stride in shorts (16B-aligned); CW = chunk width in
// shorts (CW*NCH == KT*32 REQUIRED; NCH = chunks/row; 32*NCH <= 256).
template<int KT, int LSS, int CW, bool L1>
__global__ __launch_bounds__(256) void gemm_k(
    const int* __restrict__ binoff, const float* __restrict__ inv,
    const int* __restrict__ ssrc,
    const unsigned short* __restrict__ G,    // bf16 rows [*, KT*32]
    const unsigned short* __restrict__ Bw,   // bf16 W^T [r][128][KT*32]
    const unsigned short* __restrict__ Br,   // bf16 root^T [128][KT*32]
    const float* __restrict__ bias,
    void* __restrict__ outp) {

    constexpr int ROW = KT * 32;       // bf16 per A-row
    constexpr int NCH = ROW / CW;      // chunks per row
    constexpr int CP8 = CW / 8;        // us8v (16B) loads per chunk
    static_assert(NCH * CW == ROW, "chunk covering must be exact");
    static_assert(32 * NCH <= 256, "one gather item per thread");

    __shared__ unsigned short As[2][32 * LSS];

    const int t = threadIdx.x;
    const int w = t >> 6, lane = t & 63;
    const int q = lane >> 4, m16 = lane & 15;
    const int d0 = blockIdx.x * 32;
    const int colb = w * 32;
    const bool gat = t < 32 * NCH;     // gather-active thread
    const int grow = t / NCH, gcc = t % NCH;

    f4v acc[2][2];
#pragma unroll
    for (int rt = 0; rt < 2; ++rt)
#pragma unroll
        for (int ct = 0; ct < 2; ++ct) acc[rt][ct] = f4v{0.f, 0.f, 0.f, 0.f};

    // prefetch meta + first edge row for it=0
    int so = 0, eo = 0; float iv = 0.f; us8v g0[CP8];
#pragma unroll
    for (int j = 0; j < CP8; ++j) g0[j] = us8v{};
    if (gat) {
        int b = (d0 + grow) * N_REL;
        so = binoff[b]; eo = binoff[b + 1]; iv = inv[b];
        if (so < eo) {
            const unsigned short* gp = G + (size_t)ssrc[so] * ROW + gcc * CW;
#pragma unroll
            for (int j = 0; j < CP8; ++j) g0[j] = *(const us8v*)(gp + j * 8);
        }
    }

    // B fragments for it=0
    bf8v bfr[2][KT];
#pragma unroll
    for (int ct = 0; ct < 2; ++ct) {
        const int n = colb + 16 * ct + m16;
#pragma unroll
        for (int ks = 0; ks < KT; ++ks)
            bfr[ct][ks] = *(const bf8v*)(Bw + (size_t)n * ROW + ks * 32 + q * 8);
    }

    for (int it = 0; it < N_REL; ++it) {
        // ---- gather (uses prefetched regs) -> LDS buffer it&1 ----
        unsigned short* Ab = As[it & 1];
        if (gat) {
            float a[CW];
#pragma unroll
            for (int j = 0; j < CW; ++j) a[j] = 0.f;
            if (so < eo) {
#pragma unroll
                for (int j = 0; j < CP8; ++j)
#pragma unroll
                    for (int k = 0; k < 8; ++k) a[j * 8 + k] = b2f(g0[j][k]);
                for (int p = so + 1; p < eo; ++p) {
                    const unsigned short* gp = G + (size_t)ssrc[p] * ROW + gcc * CW;
#pragma unroll
                    for (int j = 0; j < CP8; ++j) {
                        us8v g = *(const us8v*)(gp + j * 8);
#pragma unroll
                        for (int k = 0; k < 8; ++k) a[j * 8 + k] += b2f(g[k]);
                    }
                }
            }
            unsigned short* wp = &Ab[grow * LSS + gcc * CW];
#pragma unroll
            for (int j = 0; j < CP8; ++j) {
                us8v sv;
#pragma unroll
                for (int k = 0; k < 8; ++k) sv[k] = f2b(a[j * 8 + k] * iv);
                *(us8v*)(wp + j * 8) = sv;
            }
        }
        __syncthreads();

        // ---- prefetch meta + first edge for it+1 (hides behind MFMA below) ----
        if (gat && it + 1 < N_REL) {
            int b = (d0 + grow) * N_REL + it + 1;
            so = binoff[b]; eo = binoff[b + 1]; iv = inv[b];
            if (so < eo) {
                const unsigned short* gp = G + (size_t)ssrc[so] * ROW + gcc * CW;
#pragma unroll
                for (int j = 0; j < CP8; ++j) g0[j] = *(const us8v*)(gp + j * 8);
            }
        }

        // ---- A fragments + MFMA ----
#pragma unroll
        for (int rt = 0; rt < 2; ++rt) {
            const unsigned short* ar = &Ab[(m16 + 16 * rt) * LSS];
#pragma unroll
            for (int ks = 0; ks < KT; ++ks) {
                bf8v af = *(const bf8v*)(ar + ks * 32 + q * 8);
#pragma unroll
                for (int ct = 0; ct < 2; ++ct)
                    acc[rt][ct] = __builtin_amdgcn_mfma_f32_16x16x32_bf16(af, bfr[ct][ks], acc[rt][ct], 0, 0, 0);
            }
        }

        // ---- B fragments for it+1 (root weights on last iter) ----
        const unsigned short* Bp = (it + 1 < N_REL) ? (Bw + (size_t)(it + 1) * HID * ROW) : Br;
#pragma unroll
        for (int ct = 0; ct < 2; ++ct) {
            const int n = colb + 16 * ct + m16;
#pragma unroll
            for (int ks = 0; ks < KT; ++ks)
                bfr[ct][ks] = *(const bf8v*)(Bp + (size_t)n * ROW + ks * 32 + q * 8);
        }
    }

    // ---- root transform: A fragments straight from global ----
#pragma unroll
    for (int rt = 0; rt < 2; ++rt) {
#pragma unroll
        for (int ks = 0; ks < KT; ++ks) {
            bf8v af = *(const bf8v*)(G + (size_t)(d0 + m16 + 16 * rt) * ROW + ks * 32 + q * 8);
#pragma unroll
            for (int ct = 0; ct < 2; ++ct)
                acc[rt][ct] = __builtin_amdgcn_mfma_f32_16x16x32_bf16(af, bfr[ct][ks], acc[rt][ct], 0, 0, 0);
        }
    }

    // ---- epilogue: direct stores ----
#pragma unroll
    for (int ct = 0; ct < 2; ++ct) {
        const int col = colb + 16 * ct + m16;
        const float bc = bias[col];
#pragma unroll
        for (int rt = 0; rt < 2; ++rt) {
#pragma unroll
            for (int g = 0; g < 4; ++g) {
                const int rr = 16 * rt + q * 4 + g;
                if constexpr (L1) {
                    ((unsigned short*)outp)[(size_t)(d0 + rr) * HID + col] =
                        f2b(fmaxf(acc[rt][ct][g] + bc, 0.0f));
                } else {
                    ((float*)outp)[(size_t)(d0 + rr) * HID + col] = acc[rt][ct][g] + bc;
                }
            }
        }
    }
}

extern "C" void kernel_launch(void* const* d_in, const int* in_sizes, int n_in,
                              void* d_out, int out_size, void* d_ws, size_t ws_size,
                              hipStream_t stream) {
    const int*   ei    = (const int*)d_in[0];   // [2, E]
    const int*   et    = (const int*)d_in[1];   // [E]
    const float* x     = (const float*)d_in[2]; // [N, 16]
    const float* W1    = (const float*)d_in[3]; // [32, 16, 128]
    const float* root1 = (const float*)d_in[4]; // [16, 128]
    const float* b1    = (const float*)d_in[5]; // [128]
    const float* W2    = (const float*)d_in[6]; // [32, 128, 128]
    const float* root2 = (const float*)d_in[7]; // [128, 128]
    const float* b2    = (const float*)d_in[8]; // [128]
    float* out = (float*)d_out;

    // ---- workspace layout ----
    char* ws = (char*)d_ws;
    size_t off = 0;
    auto alloc = [&](size_t bytes) { void* p = ws + off; off = (off + bytes + 63) & ~(size_t)63; return p; };
    int*   hist    = (int*)  alloc((size_t)NB * 4);
    int*   binoff  = (int*)  alloc((size_t)(NB + 1) * 4);
    int*   cursors = (int*)  alloc((size_t)NB * 4);
    float* inv     = (float*)alloc((size_t)NB * 4);
    int*   bsum    = (int*)  alloc(625 * 4);
    int*   bbase   = (int*)  alloc(625 * 4);
    int*   ssrc    = (int*)  alloc((size_t)N_EDGES * 4);
    unsigned short* xb  = (unsigned short*)alloc((size_t)N_NODES * 32 * 2);
    unsigned short* h1b = (unsigned short*)alloc((size_t)N_NODES * HID * 2);
    unsigned short* w1t = (unsigned short*)alloc((size_t)N_REL * HID * 32 * 2);
    unsigned short* r1t = (unsigned short*)alloc((size_t)HID * 32 * 2);
    unsigned short* w2t = (unsigned short*)alloc((size_t)N_REL * HID * HID * 2);
    unsigned short* r2t = (unsigned short*)alloc((size_t)HID * HID * 2);

    const int* src = ei;
    const int* dst = ei + N_EDGES;

    hipMemsetAsync(hist, 0, (size_t)NB * 4, stream);

    // binning
    hist_k<<<(N_EDGES + 255) / 256, 256, 0, stream>>>(dst, et, hist);
    inv_k<<<(NB + 255) / 256, 256, 0, stream>>>(hist, inv);
    scan1_k<<<NB / 1024, 256, 0, stream>>>(hist, binoff, bsum);
    scan2_k<<<1, 1024, 0, stream>>>(bsum, bbase);
    scan3_k<<<(NB + 255) / 256, 256, 0, stream>>>(binoff, bbase, cursors);
    scatter_k<<<(N_EDGES + 255) / 256, 256, 0, stream>>>(src, dst, et, cursors, ssrc);

    // bf16 conversions
    conv_x_k<<<(N_NODES * 32 + 255) / 256, 256, 0, stream>>>(x, xb);
    conv_w1_k<<<(N_REL * HID * 32 + 255) / 256, 256, 0, stream>>>(W1, w1t);
    conv_r1_k<<<(HID * 32 + 255) / 256, 256, 0, stream>>>(root1, r1t);
    conv_w2_k<<<(N_REL * HID * HID + 255) / 256, 256, 0, stream>>>(W2, w2t);
    conv_r2_k<<<(HID * HID + 255) / 256, 256, 0, stream>>>(root2, r2t);

    // layer 1: KT=1, LSS=40 shorts (80 B rows), CW=8 -> 4 chunks/row, 128 gather threads
    gemm_k<1, 40, 8, true><<<625, 256, 0, stream>>>(
        binoff, inv, ssrc, xb, w1t, r1t, b1, h1b);

    // layer 2: KT=4, LSS=136 shorts (272 B rows), CW=16 -> 8 chunks/row, 256 gather threads
    gemm_k<4, 136, 16, false><<<625, 256, 0, stream>>>(
        binoff, inv, ssrc, h1b, w2t, r2t, b2, out);
}